// Round 11
// baseline (244.323 us; speedup 1.0000x reference)
//
#include <hip/hip_runtime.h>
#include <hip/hip_fp16.h>

#define BB 8
#define LL 1024
#define DIN 256
#define DM 512
#define HH 8
#define DH 64

typedef __attribute__((ext_vector_type(8))) short bf16x8;
typedef __attribute__((ext_vector_type(4))) float f32x4;
typedef _Float16 h2f __attribute__((ext_vector_type(2)));

__device__ __forceinline__ unsigned short f2bf(float f) {
  union { float f; unsigned u; } c; c.f = f;
  unsigned u = c.u;
  return (unsigned short)((u + 0x7fffu + ((u >> 16) & 1u)) >> 16);
}

#if defined(__has_builtin)
#if __has_builtin(__builtin_amdgcn_cvt_pk_bf16_f32)
#define HAS_PK_BF16 1
#endif
#endif

#if defined(HAS_PK_BF16)
typedef __bf16 bf2 __attribute__((ext_vector_type(2)));
__device__ __forceinline__ unsigned pk2(float lo, float hi) {
  union { bf2 v; unsigned u; } c;
  c.v = __builtin_amdgcn_cvt_pk_bf16_f32(lo, hi);
  return c.u;
}
#else
__device__ __forceinline__ unsigned pk2(float lo, float hi) {
  return ((unsigned)f2bf(hi) << 16) | f2bf(lo);
}
#endif

// lam.x*adj + lam.y*dis + t in one v_dot2_f32_f16 (device pass only;
// host pass gets a typecheck-only stub — host never executes device code)
__device__ __forceinline__ float biasdot(unsigned u, h2f lam, float t) {
#if defined(__HIP_DEVICE_COMPILE__)
  union { unsigned v; h2f hv; } c; c.v = u;
  return __builtin_amdgcn_fdot2(c.hv, lam, t, false);
#else
  (void)u; (void)lam;
  return t;
#endif
}

__device__ __forceinline__ unsigned pkh(float a, float d) {
  return (unsigned)__half_as_ushort(__float2half_rn(a)) |
         ((unsigned)__half_as_ushort(__float2half_rn(d)) << 16);
}

// async global -> LDS DMA, 16 B/lane; LDS dest = wave-uniform base + lane*16
__device__ __forceinline__ void async_copy16(void* lds, const void* g) {
  __builtin_amdgcn_global_load_lds(
      (const __attribute__((address_space(1))) unsigned*)g,
      (__attribute__((address_space(3))) unsigned*)lds, 16, 0, 0);
}

// ---------------- K0: precast (x, weights, mask) — bias-pack moved to K1 ---
// 1,738,752 quads: 3x524288 X + 3x32768 W + 65536 wo + 2048 mask. Grid 6792.
__global__ __launch_bounds__(256) void prep(
    const float* __restrict__ qin, const float* __restrict__ kin,
    const float* __restrict__ vin,
    const float* __restrict__ wq, const float* __restrict__ wk,
    const float* __restrict__ wv, const float* __restrict__ wo,
    const int* __restrict__ msk,
    unsigned short* __restrict__ xq, unsigned short* __restrict__ xk,
    unsigned short* __restrict__ xv,
    unsigned short* __restrict__ wqb, unsigned short* __restrict__ wkb,
    unsigned short* __restrict__ wvb, unsigned short* __restrict__ wob,
    float* __restrict__ mad)
{
  int t = blockIdx.x * 256 + threadIdx.x;  // quad index
  const int XS = 524288, WS = 32768;
  if (t < 3 * XS) {
    int seg = t >> 19, off = t & (XS - 1);
    const float* s = (seg == 0) ? qin : (seg == 1) ? kin : vin;
    unsigned short* d = (seg == 0) ? xq : (seg == 1) ? xk : xv;
    float4 f = ((const float4*)s)[off];
    uint2 o = { pk2(f.x, f.y), pk2(f.z, f.w) };
    ((uint2*)d)[off] = o;
    return;
  }
  t -= 3 * XS;
  if (t < 3 * WS) {
    int seg = t >> 15, off = t & (WS - 1);
    const float* s = (seg == 0) ? wq : (seg == 1) ? wk : wv;
    unsigned short* d = (seg == 0) ? wqb : (seg == 1) ? wkb : wvb;
    float4 f = ((const float4*)s)[off];
    uint2 o = { pk2(f.x, f.y), pk2(f.z, f.w) };
    ((uint2*)d)[off] = o;
    return;
  }
  t -= 3 * WS;
  if (t < 65536) {
    float4 f = ((const float4*)wo)[t];
    uint2 o = { pk2(f.x, f.y), pk2(f.z, f.w) };
    ((uint2*)wob)[t] = o;
    return;
  }
  t -= 65536;
  if (t < 2048) {
    int4 m = ((const int4*)msk)[t];
    float4 f = { m.x ? 0.0f : -30000.0f, m.y ? 0.0f : -30000.0f,
                 m.z ? 0.0f : -30000.0f, m.w ? 0.0f : -30000.0f };
    ((float4*)mad)[t] = f;
  }
}

// ---------------- K1: QKV projection + bias-pack (heterogeneous blocks) ----
// Grid 6144, 1-D. Every 4th block (bid&3==0, 1536 total) runs the GEMM
// (r10 barrier-free structure: W static LDS + wave-private X DMA dbuf with
// counted vmcnt). The other 4608 blocks grid-stride the 100 MB bias pack
// (adj,dis f32 -> packed half2). Interleaved block IDs mix the BW-bound
// pack with the latency-bound GEMM on each CU — in r0-r10 these ran as
// SERIAL kernels (prep then qkv), each leaving the other resource idle.
// Pack completes before attn reads bpk: enforced by kernel boundary.
__global__ __launch_bounds__(256) void qkv_proj(
    const unsigned short* __restrict__ xq, const unsigned short* __restrict__ xk,
    const unsigned short* __restrict__ xv,
    const unsigned short* __restrict__ wqb, const unsigned short* __restrict__ wkb,
    const unsigned short* __restrict__ wvb,
    const float* __restrict__ adj, const float* __restrict__ dis,
    unsigned* __restrict__ bp,
    unsigned short* __restrict__ qb, unsigned short* __restrict__ kb,
    unsigned short* __restrict__ vt)
{
  const int bid = blockIdx.x;
  const int tid = threadIdx.x;
  // arena: W static 32768 | X 4 waves x (2 parity x 2048) = 49152 B
  __shared__ __align__(16) char arena[49152];

  if ((bid & 3) != 0) {
    // ---- bias-pack stream: 2,097,152 quads over 4608 blocks ----
    const int pack_ord = (bid >> 2) * 3 + (bid & 3) - 1;  // 0..4607
    for (int t = pack_ord * 256 + tid; t < 2097152; t += 4608 * 256) {
      float4 a4 = ((const float4*)adj)[t];
      float4 d4 = ((const float4*)dis)[t];
      uint4 o = { pkh(a4.x, d4.x), pkh(a4.y, d4.y),
                  pkh(a4.z, d4.z), pkh(a4.w, d4.w) };
      ((uint4*)bp)[t] = o;
    }
    return;
  }

  // ---- GEMM block: decode (tensor, head, mtile) from gemm ordinal ----
  const int g = bid >> 2;             // 0..1535
  const int tz = g >> 9;              // tensor 0..2
  const int rem = g & 511;
  const int h  = rem & 7;
  const int m0 = (rem >> 3) * 128;
  const unsigned short* __restrict__ X = (tz == 0) ? xq : (tz == 1) ? xk : xv;
  const unsigned short* __restrict__ W = (tz == 0) ? wqb : (tz == 1) ? wkb : wvb;
  const int wid = tid >> 6;
  const int lane = tid & 63;
  const int lo = lane & 15;
  const int quad = lane >> 4;
  char* xpriv = arena + 32768 + wid * 4096;

  f32x4 acc[2][4];
#pragma unroll
  for (int mi = 0; mi < 2; ++mi)
#pragma unroll
    for (int ni = 0; ni < 4; ++ni) acc[mi][ni] = (f32x4)0.0f;

  // prologue: W static (8 ops; slot c of row r holds global chunk c^(r&15))
#pragma unroll
  for (int j = 0; j < 8; ++j) {
    int idx = j * 256 + tid, r = idx >> 5, c = idx & 31;
    async_copy16(arena + j * 4096 + wid * 1024,
                 W + (size_t)(h * 64 + r) * DIN + ((c ^ (r & 15)) * 8));
  }
  // X(0) wave-private -> parity 0 (2 ops; slot c of row r holds c^(r&3))
#pragma unroll
  for (int j = 0; j < 2; ++j) {
    int idx = j * 64 + lane, r = idx >> 2, c = idx & 3;
    async_copy16(xpriv + j * 1024,
                 X + (size_t)(m0 + wid * 32 + r) * DIN + ((c ^ (r & 3)) * 8));
  }
  __syncthreads();  // drains W + X(0); the only barrier

  const unsigned short* Wb = (const unsigned short*)arena;
  for (int it = 0; it < 8; ++it) {
    const int p = it & 1;
    if (it < 7) {  // X(it+1) into alt parity; vmcnt(2) retires X(it)
      const int kk = (it + 1) * 32;
#pragma unroll
      for (int j = 0; j < 2; ++j) {
        int idx = j * 64 + lane, r = idx >> 2, c = idx & 3;
        async_copy16(xpriv + (1 - p) * 2048 + j * 1024,
                     X + (size_t)(m0 + wid * 32 + r) * DIN + kk +
                         ((c ^ (r & 3)) * 8));
      }
      asm volatile("" ::: "memory");
      asm volatile("s_waitcnt vmcnt(2)" ::: "memory");
    } else {
      asm volatile("s_waitcnt vmcnt(0)" ::: "memory");
    }
    const unsigned short* Ab = (const unsigned short*)(xpriv + p * 2048);
    bf16x8 a[2], bfr[4];
#pragma unroll
    for (int mi = 0; mi < 2; ++mi) {
      int R = mi * 16 + lo;
      a[mi] = *(const bf16x8*)&Ab[R * 32 + ((quad ^ (R & 3)) * 8)];
    }
#pragma unroll
    for (int ni = 0; ni < 4; ++ni) {
      int N = ni * 16 + lo;
      bfr[ni] = *(const bf16x8*)&Wb[N * 256 + (((it * 4 + quad) ^ (N & 15)) * 8)];
    }
#pragma unroll
    for (int mi = 0; mi < 2; ++mi)
#pragma unroll
      for (int ni = 0; ni < 4; ++ni)
        acc[mi][ni] = __builtin_amdgcn_mfma_f32_16x16x32_bf16(
            a[mi], bfr[ni], acc[mi][ni], 0, 0, 0);
  }

  const int b = m0 >> 10;
  const int lbase0 = (m0 & 1023) + wid * 32;
  if (tz < 2) {
    unsigned short* dstp = (tz == 0) ? qb : kb;
#pragma unroll
    for (int mi = 0; mi < 2; ++mi)
#pragma unroll
      for (int ni = 0; ni < 4; ++ni) {
        int d = ni * 16 + lo;
#pragma unroll
        for (int r = 0; r < 4; ++r) {
          int lb = lbase0 + mi * 16 + quad * 4 + r;
          dstp[((size_t)(b * HH + h) * LL + lb) * DH + d] = f2bf(acc[mi][ni][r]);
        }
      }
  } else {
#pragma unroll
    for (int mi = 0; mi < 2; ++mi)
#pragma unroll
      for (int ni = 0; ni < 4; ++ni) {
        int d = ni * 16 + lo;
        int lb = lbase0 + quad * 8 + mi * 4;  // phi-permuted within 32-block
        uint2 o = { pk2(acc[mi][ni][0], acc[mi][ni][1]),
                    pk2(acc[mi][ni][2], acc[mi][ni][3]) };
        *(uint2*)&vt[((size_t)(b * HH + h) * DH + d) * LL + lb] = o;
      }
  }
}

// ---------------- K2: fused biased attention (r7 exact — best measured) ----
// r0 DMA pipeline + pbuf eliminated (lane-local P via phi identity; V^T
// pre-permuted in K1). Empty asm memory fence pins the DMA/V/mask issue at
// tile top (r6 lesson). LDS 49152 (K 32K + bias 16K) => 3 blocks/CU.
// grid 1024: idx = qt*32 + hg*8 + b. 4 waves: (h = hg*2 + wid&1, kh = wid>>1).
__global__ __launch_bounds__(256) void attn(
    const unsigned short* __restrict__ qb, const unsigned short* __restrict__ kb,
    const unsigned short* __restrict__ vt,
    const float* __restrict__ mad, const unsigned* __restrict__ bp,
    const float* __restrict__ la_, const float* __restrict__ ld_,
    unsigned short* __restrict__ ao)
{
  const int bi = blockIdx.x;
  const int b  = bi & 7;
  const int hg = (bi >> 3) & 3;
  const int q0 = (bi >> 5) * 32;
  const int tid = threadIdx.x;
  const int wid = tid >> 6;
  const int lane = tid & 63;
  const int lo = lane & 15;
  const int quad = lane >> 4;
  const int h  = hg * 2 + (wid & 1);
  const int kh = wid >> 1;
  const int bh = b * HH + h;

  // arena: kbuf 2x16384 | bbuf 2x8192 = 49152 B; merge alias (17408 B) after.
  __shared__ __align__(16) char arena[49152];
  float* mgbuf = (float*)arena;  // merge alias (post-loop, stage bufs dead)

  const float LOG2E = 1.44269504f;
  const float la2 = la_[h] * LOG2E, ld2 = ld_[h] * LOG2E;
  const float sc2 = 0.125f * LOG2E;
  h2f lam2;
  lam2.x = (_Float16)la2;
  lam2.y = (_Float16)ld2;

  const unsigned short* qp = qb + ((size_t)bh * LL + q0) * DH;
  bf16x8 qB[2][2];
#pragma unroll
  for (int nj = 0; nj < 2; ++nj)
#pragma unroll
    for (int ki = 0; ki < 2; ++ki)
      qB[nj][ki] = *(const bf16x8*)&qp[(nj * 16 + lo) * DH + ki * 32 + quad * 8];

  const unsigned short* kp = kb + (size_t)bh * LL * DH;
  const unsigned short* vp = vt + (size_t)bh * DH * LL;
  const unsigned* bpp = bp + ((size_t)b * LL + q0) * LL;
  const float* mp = mad + b * LL;

  f32x4 o[4][2];
  float rs[2] = {0.0f, 0.0f};
#pragma unroll
  for (int md = 0; md < 4; ++md)
#pragma unroll
    for (int nj = 0; nj < 2; ++nj) o[md][nj] = (f32x4)0.0f;

  const int kbeg = kh * (LL / 2);
  const int r8 = lane >> 3, p8 = lane & 7;

  // stage tile 0 -> parity 0 (K: all waves; bias: waves 0,2)
  {
    const unsigned short* kg = kp + (size_t)kbeg * DH;
#pragma unroll
    for (int j = 0; j < 4; ++j)
      async_copy16(arena + wid * 4096 + j * 1024,
                   kg + (j * 8 + r8) * 64 + ((p8 ^ r8) * 8));
    if ((wid & 1) == 0) {
      const int khs = wid >> 1;
      const unsigned* bg = bpp + khs * (LL / 2);
#pragma unroll
      for (int j = 0; j < 4; ++j)
        async_copy16(arena + 32768 + khs * 4096 + j * 1024,
                     bg + (size_t)(j * 8 + r8) * LL + ((p8 ^ r8) * 4));
    }
  }
  __syncthreads();

  for (int jt = 0; jt < 16; ++jt) {
    const int p = jt & 1;
    const int k0 = kbeg + jt * 32;

    if (jt < 15) {  // prefetch tile+1 into alt parity
      const int kn = k0 + 32, q = 1 - p;
      const unsigned short* kg = kp + (size_t)kn * DH;
#pragma unroll
      for (int j = 0; j < 4; ++j)
        async_copy16(arena + q * 16384 + wid * 4096 + j * 1024,
                     kg + (j * 8 + r8) * 64 + ((p8 ^ r8) * 8));
      if ((wid & 1) == 0) {
        const int khs = wid >> 1;
        const unsigned* bg = bpp + khs * (LL / 2) + (jt + 1) * 32;
#pragma unroll
        for (int j = 0; j < 4; ++j)
          async_copy16(arena + 32768 + q * 8192 + khs * 4096 + j * 1024,
                       bg + (size_t)(j * 8 + r8) * LL + ((p8 ^ r8) * 4));
      }
    }

    // V (phi-ordered in memory: single 16B read) + mask, issued at tile top
    bf16x8 vA[4];
#pragma unroll
    for (int md = 0; md < 4; ++md)
      vA[md] = *(const bf16x8*)&vp[(md * 16 + lo) * LL + k0 + quad * 8];
    f32x4 msv[2];
#pragma unroll
    for (int mi = 0; mi < 2; ++mi)
      msv[mi] = *(const f32x4*)&mp[k0 + mi * 16 + quad * 4];

    // pin issue cluster above compute (no VGPR cost)
    asm volatile("" ::: "memory");

    // ---- consume K parity p: QK^T ----
    const unsigned short* kbf = (const unsigned short*)(arena + p * 16384) + wid * 2048;
    bf16x8 kA[2][2];
#pragma unroll
    for (int mi = 0; mi < 2; ++mi)
#pragma unroll
      for (int ki = 0; ki < 2; ++ki)
        kA[mi][ki] = *(const bf16x8*)&kbf[(mi * 16 + lo) * 64 +
                                          (((ki * 4 + quad) ^ (lo & 7)) * 8)];
    f32x4 s[2][2];
#pragma unroll
    for (int mi = 0; mi < 2; ++mi)
#pragma unroll
      for (int nj = 0; nj < 2; ++nj) s[mi][nj] = (f32x4)0.0f;
#pragma unroll
    for (int ki = 0; ki < 2; ++ki)
#pragma unroll
      for (int mi = 0; mi < 2; ++mi)
#pragma unroll
        for (int nj = 0; nj < 2; ++nj)
          s[mi][nj] = __builtin_amdgcn_mfma_f32_16x16x32_bf16(
              kA[mi][ki], qB[nj][ki], s[mi][nj], 0, 0, 0);

    // bias (LDS parity p) + softmax-numerator + lane-local pack to B-frag
    const unsigned* bbf = (const unsigned*)(arena + 32768 + p * 8192) + kh * 1024;
    unsigned pw[2][4];
#pragma unroll
    for (int mi = 0; mi < 2; ++mi)
#pragma unroll
      for (int nj = 0; nj < 2; ++nj) {
        uint4 u = *(const uint4*)&bbf[(nj * 16 + lo) * 32 +
                                      (((mi * 4 + quad) ^ (lo & 7)) * 4)];
        float p4[4];
#pragma unroll
        for (int r = 0; r < 4; ++r) {
          float tb = fmaf(s[mi][nj][r], sc2, msv[mi][r]);
          p4[r] = __builtin_amdgcn_exp2f(biasdot(u[r], lam2, tb));
        }
        rs[nj] += (p4[0] + p4[1]) + (p4[2] + p4[3]);
        pw[nj][mi * 2]     = pk2(p4[0], p4[1]);
        pw[nj][mi * 2 + 1] = pk2(p4[2], p4[3]);
      }
    bf16x8 pB[2];
#pragma unroll
    for (int nj = 0; nj < 2; ++nj) {
      union { unsigned u[4]; bf16x8 v; } pc;
      pc.u[0] = pw[nj][0]; pc.u[1] = pw[nj][1];
      pc.u[2] = pw[nj][2]; pc.u[3] = pw[nj][3];
      pB[nj] = pc.v;
    }

    // PV (phi cancels between pre-permuted V and lane-local P)
#pragma unroll
    for (int md = 0; md < 4; ++md)
#pragma unroll
      for (int nj = 0; nj < 2; ++nj)
        o[md][nj] = __builtin_amdgcn_mfma_f32_16x16x32_bf16(
            vA[md], pB[nj], o[md][nj], 0, 0, 0);

    __syncthreads();  // drains own DMA (tile+1) + protects parity flip
  }

  // merge the two K-halves (mgbuf aliases stage buffers, dead now)
  const int hs = wid & 1;
  if (kh == 1) {
#pragma unroll
    for (int md = 0; md < 4; ++md)
#pragma unroll
      for (int nj = 0; nj < 2; ++nj)
#pragma unroll
        for (int r = 0; r < 4; ++r)
          mgbuf[hs * 2176 + ((md * 2 + nj) * 4 + r) * 64 + lane] = o[md][nj][r];
    mgbuf[hs * 2176 + 32 * 64 + lane] = rs[0];
    mgbuf[hs * 2176 + 33 * 64 + lane] = rs[1];
  }
  __syncthreads();
  if (kh == 0) {
#pragma unroll
    for (int md = 0; md < 4; ++md)
#pragma unroll
      for (int nj = 0; nj < 2; ++nj)
#pragma unroll
        for (int r = 0; r < 4; ++r)
          o[md][nj][r] += mgbuf[hs * 2176 + ((md * 2 + nj) * 4 + r) * 64 + lane];
    rs[0] += mgbuf[hs * 2176 + 32 * 64 + lane];
    rs[1] += mgbuf[hs * 2176 + 33 * 64 + lane];
    float inv[2];
#pragma unroll
    for (int nj = 0; nj < 2; ++nj) {
      rs[nj] += __shfl_xor(rs[nj], 16);
      rs[nj] += __shfl_xor(rs[nj], 32);
      inv[nj] = __builtin_amdgcn_rcpf(rs[nj]);
    }
#pragma unroll
    for (int md = 0; md < 4; ++md)
#pragma unroll
      for (int nj = 0; nj < 2; ++nj) {
        int l = q0 + nj * 16 + lo;
        uint2 st = { pk2(o[md][nj][0] * inv[nj], o[md][nj][1] * inv[nj]),
                     pk2(o[md][nj][2] * inv[nj], o[md][nj][3] * inv[nj]) };
        *(uint2*)&ao[((size_t)b * LL + l) * DM + h * DH + md * 16 + quad * 4] = st;
      }
  }
}

// ---------------- K3: output projection, barrier-free K-loop ---------------
// grid (8 ntile, 64 mtile), block 256 (4 waves). wob slice (64x512) staged
// ONCE into static LDS; ao rows wave-private DMA double-buffered with
// counted vmcnt(2) per K-iter. One prologue barrier, none in the loop.
__global__ __launch_bounds__(256) void oproj(
    const unsigned short* __restrict__ ao, const unsigned short* __restrict__ wob,
    float* __restrict__ out)
{
  const int m0 = blockIdx.y * 128;
  const int n0 = blockIdx.x * 64;
  // arena: W static 65536 | X 4 waves x (2 parity x 2048) = 81920 B
  __shared__ __align__(16) char arena[81920];
  const int tid = threadIdx.x;
  const int wid = tid >> 6;
  const int lane = tid & 63;
  const int lo = lane & 15;
  const int quad = lane >> 4;
  char* xpriv = arena + 65536 + wid * 4096;

  f32x4 acc[2][4];
#pragma unroll
  for (int mi = 0; mi < 2; ++mi)
#pragma unroll
    for (int ni = 0; ni < 4; ++ni) acc[mi][ni] = (f32x4)0.0f;

  // prologue: wob slice static (16 ops; slot c of row r holds chunk c^(r&15))
#pragma unroll
  for (int j = 0; j < 16; ++j) {
    int idx = j * 256 + tid, r = idx >> 6, c = idx & 63;
    async_copy16(arena + j * 4096 + wid * 1024,
                 wob + (size_t)(n0 + r) * DM + ((c ^ (r & 15)) * 8));
  }
  // X(0) = ao rows wid*32.. -> parity 0
#pragma unroll
  for (int j = 0; j < 2; ++j) {
    int idx = j * 64 + lane, r = idx >> 2, c = idx & 3;
    async_copy16(xpriv + j * 1024,
                 ao + (size_t)(m0 + wid * 32 + r) * DM + ((c ^ (r & 3)) * 8));
  }
  __syncthreads();  // the only barrier

  const unsigned short* Wb = (const unsigned short*)arena;
  for (int it = 0; it < 16; ++it) {
    const int p = it & 1;
    if (it < 15) {
      const int kk = (it + 1) * 32;
#pragma unroll
      for (int j = 0; j < 2; ++j) {
        int idx = j * 64 + lane, r = idx >> 2, c = idx & 3;
        async_copy16(xpriv + (1 - p) * 2048 + j * 1024,
                     ao + (size_t)(m0 + wid * 32 + r) * DM + kk +
                         ((c ^ (r & 3)) * 8));
      }
      asm volatile("" ::: "memory");
      asm volatile("s_waitcnt vmcnt(2)" ::: "memory");
    } else {
      asm volatile("s_waitcnt vmcnt(0)" ::: "memory");
    }
    const unsigned short* Ab = (const unsigned short*)(xpriv + p * 2048);
    bf16x8 a[2], bfr[4];
#pragma unroll
    for (int mi = 0; mi < 2; ++mi) {
      int R = mi * 16 + lo;
      a[mi] = *(const bf16x8*)&Ab[R * 32 + ((quad ^ (R & 3)) * 8)];
    }
#pragma unroll
    for (int ni = 0; ni < 4; ++ni) {
      int N = ni * 16 + lo;
      bfr[ni] = *(const bf16x8*)&Wb[N * 512 + (((it * 4 + quad) ^ (N & 15)) * 8)];
    }
#pragma unroll
    for (int mi = 0; mi < 2; ++mi)
#pragma unroll
      for (int ni = 0; ni < 4; ++ni)
        acc[mi][ni] = __builtin_amdgcn_mfma_f32_16x16x32_bf16(
            a[mi], bfr[ni], acc[mi][ni], 0, 0, 0);
  }

#pragma unroll
  for (int mi = 0; mi < 2; ++mi)
#pragma unroll
    for (int ni = 0; ni < 4; ++ni)
#pragma unroll
      for (int r = 0; r < 4; ++r)
        out[(size_t)(m0 + wid * 32 + mi * 16 + quad * 4 + r) * DM +
            n0 + ni * 16 + lo] = acc[mi][ni][r];
}

extern "C" void kernel_launch(void* const* d_in, const int* in_sizes, int n_in,
                              void* d_out, int out_size, void* d_ws, size_t ws_size,
                              hipStream_t stream) {
  const float* qin = (const float*)d_in[0];
  const float* kin = (const float*)d_in[1];
  const float* vin = (const float*)d_in[2];
  const int*   msk = (const int*)d_in[3];
  const float* adj = (const float*)d_in[4];
  const float* dis = (const float*)d_in[5];
  const float* wq  = (const float*)d_in[6];
  const float* wk  = (const float*)d_in[7];
  const float* wv  = (const float*)d_in[8];
  const float* wo  = (const float*)d_in[9];
  const float* la  = (const float*)d_in[10];
  const float* ld  = (const float*)d_in[11];
  float* out = (float*)d_out;

  const size_t tensb = (size_t)BB * HH * LL * DH;   // 4,194,304
  const size_t xsz   = (size_t)BB * LL * DIN;       // 2,097,152
  unsigned short* qb  = (unsigned short*)d_ws;
  unsigned short* kb  = qb + tensb;
  unsigned short* vt  = kb + tensb;
  unsigned short* ao  = vt + tensb;                 // (B,L,512) bf16
  unsigned short* xq  = ao;                         // alias (dead until attn)
  unsigned short* xk  = ao + xsz;
  unsigned short* xv  = ao + tensb;
  unsigned short* wqb = xv + xsz;
  unsigned short* wkb = wqb + (size_t)DM * DIN;
  unsigned short* wvb = wkb + (size_t)DM * DIN;
  unsigned short* wob = wvb + (size_t)DM * DIN;
  float*          mdd = (float*)(wob + (size_t)DM * DM);
  unsigned*       bpk = (unsigned*)(mdd + (size_t)BB * LL);  // 33.5 MB packed bias

  prep<<<dim3(6792), 256, 0, stream>>>(qin, kin, vin, wq, wk, wv, wo, msk,
                                       xq, xk, xv, wqb, wkb, wvb, wob, mdd);
  qkv_proj<<<dim3(6144), 256, 0, stream>>>(xq, xk, xv, wqb, wkb, wvb,
                                           adj, dis, bpk, qb, kb, vt);
  attn<<<dim3(1024), 256, 0, stream>>>(qb, kb, vt, mdd, bpk, la, ld, ao);
  oproj<<<dim3(8, 64), 256, 0, stream>>>(ao, wob, out);
}

// Round 12
// 230.732 us; speedup vs baseline: 1.0589x; 1.0589x over previous
//
#include <hip/hip_runtime.h>
#include <hip/hip_fp16.h>

#define BB 8
#define LL 1024
#define DIN 256
#define DM 512
#define HH 8
#define DH 64

typedef __attribute__((ext_vector_type(8))) short bf16x8;
typedef __attribute__((ext_vector_type(4))) float f32x4;

__device__ __forceinline__ unsigned short f2bf(float f) {
  union { float f; unsigned u; } c; c.f = f;
  unsigned u = c.u;
  return (unsigned short)((u + 0x7fffu + ((u >> 16) & 1u)) >> 16);
}

#if defined(__has_builtin)
#if __has_builtin(__builtin_amdgcn_cvt_pk_bf16_f32)
#define HAS_PK_BF16 1
#endif
#endif

#if defined(HAS_PK_BF16)
typedef __bf16 bf2 __attribute__((ext_vector_type(2)));
__device__ __forceinline__ unsigned pk2(float lo, float hi) {
  union { bf2 v; unsigned u; } c;
  c.v = __builtin_amdgcn_cvt_pk_bf16_f32(lo, hi);
  return c.u;
}
#else
__device__ __forceinline__ unsigned pk2(float lo, float hi) {
  return ((unsigned)f2bf(hi) << 16) | f2bf(lo);
}
#endif

// 16-bit bias pack: dis as f16 rounded to the 15-bit (even-LSB) grid,
// binary adj in the stolen LSB. Halves bias bytes vs half2 (attn is a
// bytes-proportional streamer: r0-r11 all measure dur = hbm_bytes/~640GB/s).
__device__ __forceinline__ unsigned pk16(float a, float d) {
  unsigned v = (unsigned)__half_as_ushort(__float2half_rn(d));
  v = (v + 1u) & 0xFFFEu;           // round-to-nearest on 15-bit grid
  return v | (a > 0.5f ? 1u : 0u);
}
__device__ __forceinline__ unsigned pk16x2(float a0, float d0,
                                           float a1, float d1) {
  return pk16(a0, d0) | (pk16(a1, d1) << 16);
}

// async global -> LDS DMA, 16 B/lane; LDS dest = wave-uniform base + lane*16
__device__ __forceinline__ void async_copy16(void* lds, const void* g) {
  __builtin_amdgcn_global_load_lds(
      (const __attribute__((address_space(1))) unsigned*)g,
      (__attribute__((address_space(3))) unsigned*)lds, 16, 0, 0);
}

// ---------------- K0: merged precast (bias pack now u16) ----------------
// quads: 3x524288 X + 3x32768 W + 65536 wo + 2048 mask + 1048576 pack(8/thr)
// = 2,787,328 -> grid 10888.
__global__ __launch_bounds__(256) void prep(
    const float* __restrict__ qin, const float* __restrict__ kin,
    const float* __restrict__ vin,
    const float* __restrict__ wq, const float* __restrict__ wk,
    const float* __restrict__ wv, const float* __restrict__ wo,
    const int* __restrict__ msk,
    const float* __restrict__ adj, const float* __restrict__ dis,
    unsigned short* __restrict__ xq, unsigned short* __restrict__ xk,
    unsigned short* __restrict__ xv,
    unsigned short* __restrict__ wqb, unsigned short* __restrict__ wkb,
    unsigned short* __restrict__ wvb, unsigned short* __restrict__ wob,
    float* __restrict__ mad, unsigned short* __restrict__ bp)
{
  int t = blockIdx.x * 256 + threadIdx.x;
  const int XS = 524288, WS = 32768;
  if (t < 3 * XS) {
    int seg = t >> 19, off = t & (XS - 1);
    const float* s = (seg == 0) ? qin : (seg == 1) ? kin : vin;
    unsigned short* d = (seg == 0) ? xq : (seg == 1) ? xk : xv;
    float4 f = ((const float4*)s)[off];
    uint2 o = { pk2(f.x, f.y), pk2(f.z, f.w) };
    ((uint2*)d)[off] = o;
    return;
  }
  t -= 3 * XS;
  if (t < 3 * WS) {
    int seg = t >> 15, off = t & (WS - 1);
    const float* s = (seg == 0) ? wq : (seg == 1) ? wk : wv;
    unsigned short* d = (seg == 0) ? wqb : (seg == 1) ? wkb : wvb;
    float4 f = ((const float4*)s)[off];
    uint2 o = { pk2(f.x, f.y), pk2(f.z, f.w) };
    ((uint2*)d)[off] = o;
    return;
  }
  t -= 3 * WS;
  if (t < 65536) {
    float4 f = ((const float4*)wo)[t];
    uint2 o = { pk2(f.x, f.y), pk2(f.z, f.w) };
    ((uint2*)wob)[t] = o;
    return;
  }
  t -= 65536;
  if (t < 2048) {
    int4 m = ((const int4*)msk)[t];
    float4 f = { m.x ? 0.0f : -30000.0f, m.y ? 0.0f : -30000.0f,
                 m.z ? 0.0f : -30000.0f, m.w ? 0.0f : -30000.0f };
    ((float4*)mad)[t] = f;
    return;
  }
  t -= 2048;  // u16 bias pack: 1,048,576 threads x 8 elements
  if (t < 1048576) {
    float4 a0 = ((const float4*)adj)[t * 2];
    float4 a1 = ((const float4*)adj)[t * 2 + 1];
    float4 d0 = ((const float4*)dis)[t * 2];
    float4 d1 = ((const float4*)dis)[t * 2 + 1];
    uint4 o = { pk16x2(a0.x, d0.x, a0.y, d0.y),
                pk16x2(a0.z, d0.z, a0.w, d0.w),
                pk16x2(a1.x, d1.x, a1.y, d1.y),
                pk16x2(a1.z, d1.z, a1.w, d1.w) };
    ((uint4*)bp)[t] = o;
  }
}

// ---------------- K1: QKV projection, barrier-free K-loop (r10) ------------
__global__ __launch_bounds__(256) void qkv_proj(
    const unsigned short* __restrict__ xq, const unsigned short* __restrict__ xk,
    const unsigned short* __restrict__ xv,
    const unsigned short* __restrict__ wqb, const unsigned short* __restrict__ wkb,
    const unsigned short* __restrict__ wvb,
    unsigned short* __restrict__ qb, unsigned short* __restrict__ kb,
    unsigned short* __restrict__ vt)
{
  const int t = blockIdx.z;
  const unsigned short* __restrict__ X = (t == 0) ? xq : (t == 1) ? xk : xv;
  const unsigned short* __restrict__ W = (t == 0) ? wqb : (t == 1) ? wkb : wvb;
  const int m0 = blockIdx.y * 128;
  const int h  = blockIdx.x;
  // arena: W static 32768 | X 4 waves x (2 parity x 2048) = 49152 B
  __shared__ __align__(16) char arena[49152];
  const int tid = threadIdx.x;
  const int wid = tid >> 6;
  const int lane = tid & 63;
  const int lo = lane & 15;
  const int quad = lane >> 4;
  char* xpriv = arena + 32768 + wid * 4096;

  f32x4 acc[2][4];
#pragma unroll
  for (int mi = 0; mi < 2; ++mi)
#pragma unroll
    for (int ni = 0; ni < 4; ++ni) acc[mi][ni] = (f32x4)0.0f;

#pragma unroll
  for (int j = 0; j < 8; ++j) {
    int idx = j * 256 + tid, r = idx >> 5, c = idx & 31;
    async_copy16(arena + j * 4096 + wid * 1024,
                 W + (size_t)(h * 64 + r) * DIN + ((c ^ (r & 15)) * 8));
  }
#pragma unroll
  for (int j = 0; j < 2; ++j) {
    int idx = j * 64 + lane, r = idx >> 2, c = idx & 3;
    async_copy16(xpriv + j * 1024,
                 X + (size_t)(m0 + wid * 32 + r) * DIN + ((c ^ (r & 3)) * 8));
  }
  __syncthreads();  // drains W + X(0); the only barrier

  const unsigned short* Wb = (const unsigned short*)arena;
  for (int it = 0; it < 8; ++it) {
    const int p = it & 1;
    if (it < 7) {
      const int kk = (it + 1) * 32;
#pragma unroll
      for (int j = 0; j < 2; ++j) {
        int idx = j * 64 + lane, r = idx >> 2, c = idx & 3;
        async_copy16(xpriv + (1 - p) * 2048 + j * 1024,
                     X + (size_t)(m0 + wid * 32 + r) * DIN + kk +
                         ((c ^ (r & 3)) * 8));
      }
      asm volatile("" ::: "memory");
      asm volatile("s_waitcnt vmcnt(2)" ::: "memory");
    } else {
      asm volatile("s_waitcnt vmcnt(0)" ::: "memory");
    }
    const unsigned short* Ab = (const unsigned short*)(xpriv + p * 2048);
    bf16x8 a[2], bfr[4];
#pragma unroll
    for (int mi = 0; mi < 2; ++mi) {
      int R = mi * 16 + lo;
      a[mi] = *(const bf16x8*)&Ab[R * 32 + ((quad ^ (R & 3)) * 8)];
    }
#pragma unroll
    for (int ni = 0; ni < 4; ++ni) {
      int N = ni * 16 + lo;
      bfr[ni] = *(const bf16x8*)&Wb[N * 256 + (((it * 4 + quad) ^ (N & 15)) * 8)];
    }
#pragma unroll
    for (int mi = 0; mi < 2; ++mi)
#pragma unroll
      for (int ni = 0; ni < 4; ++ni)
        acc[mi][ni] = __builtin_amdgcn_mfma_f32_16x16x32_bf16(
            a[mi], bfr[ni], acc[mi][ni], 0, 0, 0);
  }

  const int b = m0 >> 10;
  const int lbase0 = (m0 & 1023) + wid * 32;
  if (t < 2) {
    unsigned short* dstp = (t == 0) ? qb : kb;
#pragma unroll
    for (int mi = 0; mi < 2; ++mi)
#pragma unroll
      for (int ni = 0; ni < 4; ++ni) {
        int d = ni * 16 + lo;
#pragma unroll
        for (int r = 0; r < 4; ++r) {
          int lb = lbase0 + mi * 16 + quad * 4 + r;
          dstp[((size_t)(b * HH + h) * LL + lb) * DH + d] = f2bf(acc[mi][ni][r]);
        }
      }
  } else {
#pragma unroll
    for (int mi = 0; mi < 2; ++mi)
#pragma unroll
      for (int ni = 0; ni < 4; ++ni) {
        int d = ni * 16 + lo;
        int lb = lbase0 + quad * 8 + mi * 4;  // phi-permuted within 32-block
        uint2 o = { pk2(acc[mi][ni][0], acc[mi][ni][1]),
                    pk2(acc[mi][ni][2], acc[mi][ni][3]) };
        *(uint2*)&vt[((size_t)(b * HH + h) * DH + d) * LL + lb] = o;
      }
  }
}

// ---------------- K2: fused biased attention (r7 + u16 bias) ---------------
// r7 structure (best measured) with bias halved to u16 (f16 dis | adj LSB):
// bias DMA 4->2 ops/tile, bbuf 16K->8K, arena 49152->40960 = EXACTLY 4
// blocks/CU (grid 1024 fully co-resident, no tail round). Bias LDS chunk
// swizzle: chunk c of row r stored at c^(r&6) (even XOR keeps DMA 16B
// blocks intact); read chunk (mi*4+quad)^(lo&6) -> 2-way banks (free).
// Unpack: dv = f16(x&~1), adj = x&1; lambda applied in f32 (more accurate
// than old f16 fdot2).
__global__ __launch_bounds__(256) void attn(
    const unsigned short* __restrict__ qb, const unsigned short* __restrict__ kb,
    const unsigned short* __restrict__ vt,
    const float* __restrict__ mad, const unsigned short* __restrict__ bp,
    const float* __restrict__ la_, const float* __restrict__ ld_,
    unsigned short* __restrict__ ao)
{
  const int bi = blockIdx.x;
  const int b  = bi & 7;
  const int hg = (bi >> 3) & 3;
  const int q0 = (bi >> 5) * 32;
  const int tid = threadIdx.x;
  const int wid = tid >> 6;
  const int lane = tid & 63;
  const int lo = lane & 15;
  const int quad = lane >> 4;
  const int h  = hg * 2 + (wid & 1);
  const int kh = wid >> 1;
  const int bh = b * HH + h;

  // arena: kbuf 2x16384 | bbuf 2x4096 = 40960 B; merge alias (17408 B) after.
  __shared__ __align__(16) char arena[40960];
  float* mgbuf = (float*)arena;  // merge alias (post-loop, stage bufs dead)

  const float LOG2E = 1.44269504f;
  const float la2 = la_[h] * LOG2E, ld2 = ld_[h] * LOG2E;
  const float sc2 = 0.125f * LOG2E;

  const unsigned short* qp = qb + ((size_t)bh * LL + q0) * DH;
  bf16x8 qB[2][2];
#pragma unroll
  for (int nj = 0; nj < 2; ++nj)
#pragma unroll
    for (int ki = 0; ki < 2; ++ki)
      qB[nj][ki] = *(const bf16x8*)&qp[(nj * 16 + lo) * DH + ki * 32 + quad * 8];

  const unsigned short* kp = kb + (size_t)bh * LL * DH;
  const unsigned short* vp = vt + (size_t)bh * DH * LL;
  const unsigned short* bpp = bp + ((size_t)b * LL + q0) * LL;
  const float* mp = mad + b * LL;

  f32x4 o[4][2];
  float rs[2] = {0.0f, 0.0f};
#pragma unroll
  for (int md = 0; md < 4; ++md)
#pragma unroll
    for (int nj = 0; nj < 2; ++nj) o[md][nj] = (f32x4)0.0f;

  const int kbeg = kh * (LL / 2);
  const int r8 = lane >> 3, p8 = lane & 7;
  const int br = lane >> 2;            // bias row within 16-row group
  const int bsw = ((((lane & 3) << 1) ^ (br & 6)) << 2);  // u16 col, swizzled

  // stage tile 0 -> parity 0 (K: all waves; bias: waves 0,2)
  {
    const unsigned short* kg = kp + (size_t)kbeg * DH;
#pragma unroll
    for (int j = 0; j < 4; ++j)
      async_copy16(arena + wid * 4096 + j * 1024,
                   kg + (j * 8 + r8) * 64 + ((p8 ^ r8) * 8));
    if ((wid & 1) == 0) {
      const int khs = wid >> 1;
      const unsigned short* bg = bpp + khs * (LL / 2);
#pragma unroll
      for (int j = 0; j < 2; ++j)
        async_copy16(arena + 32768 + khs * 2048 + j * 1024,
                     bg + (size_t)(j * 16 + br) * LL + bsw);
    }
  }
  __syncthreads();

  for (int jt = 0; jt < 16; ++jt) {
    const int p = jt & 1;
    const int k0 = kbeg + jt * 32;

    if (jt < 15) {  // prefetch tile+1 into alt parity
      const int kn = k0 + 32, q = 1 - p;
      const unsigned short* kg = kp + (size_t)kn * DH;
#pragma unroll
      for (int j = 0; j < 4; ++j)
        async_copy16(arena + q * 16384 + wid * 4096 + j * 1024,
                     kg + (j * 8 + r8) * 64 + ((p8 ^ r8) * 8));
      if ((wid & 1) == 0) {
        const int khs = wid >> 1;
        const unsigned short* bg = bpp + khs * (LL / 2) + (jt + 1) * 32;
#pragma unroll
        for (int j = 0; j < 2; ++j)
          async_copy16(arena + 32768 + q * 4096 + khs * 2048 + j * 1024,
                       bg + (size_t)(j * 16 + br) * LL + bsw);
      }
    }

    // V (phi-ordered in memory: single 16B read) + mask, issued at tile top
    bf16x8 vA[4];
#pragma unroll
    for (int md = 0; md < 4; ++md)
      vA[md] = *(const bf16x8*)&vp[(md * 16 + lo) * LL + k0 + quad * 8];
    f32x4 msv[2];
#pragma unroll
    for (int mi = 0; mi < 2; ++mi)
      msv[mi] = *(const f32x4*)&mp[k0 + mi * 16 + quad * 4];

    // pin issue cluster above compute (no VGPR cost)
    asm volatile("" ::: "memory");

    // ---- consume K parity p: QK^T ----
    const unsigned short* kbf = (const unsigned short*)(arena + p * 16384) + wid * 2048;
    bf16x8 kA[2][2];
#pragma unroll
    for (int mi = 0; mi < 2; ++mi)
#pragma unroll
      for (int ki = 0; ki < 2; ++ki)
        kA[mi][ki] = *(const bf16x8*)&kbf[(mi * 16 + lo) * 64 +
                                          (((ki * 4 + quad) ^ (lo & 7)) * 8)];
    f32x4 s[2][2];
#pragma unroll
    for (int mi = 0; mi < 2; ++mi)
#pragma unroll
      for (int nj = 0; nj < 2; ++nj) s[mi][nj] = (f32x4)0.0f;
#pragma unroll
    for (int ki = 0; ki < 2; ++ki)
#pragma unroll
      for (int mi = 0; mi < 2; ++mi)
#pragma unroll
        for (int nj = 0; nj < 2; ++nj)
          s[mi][nj] = __builtin_amdgcn_mfma_f32_16x16x32_bf16(
              kA[mi][ki], qB[nj][ki], s[mi][nj], 0, 0, 0);

    // bias (u16 LDS, parity p) + softmax-numerator + lane-local pack
    const unsigned short* bbf =
        (const unsigned short*)(arena + 32768 + p * 4096) + kh * 1024;
    unsigned pw[2][4];
#pragma unroll
    for (int mi = 0; mi < 2; ++mi)
#pragma unroll
      for (int nj = 0; nj < 2; ++nj) {
        uint2 w = *(const uint2*)&bbf[(nj * 16 + lo) * 32 +
                                      (((mi * 4 + quad) ^ (lo & 6)) << 2)];
        float p4[4];
#pragma unroll
        for (int r = 0; r < 4; ++r) {
          unsigned xr = (((r & 2) ? w.y : w.x) >> ((r & 1) * 16)) & 0xFFFFu;
          float dv = __half2float(__ushort_as_half(
              (unsigned short)(xr & 0xFFFEu)));
          float tb = fmaf(s[mi][nj][r], sc2, msv[mi][r]);
          tb = fmaf(dv, ld2, tb);
          tb += (xr & 1u) ? la2 : 0.0f;
          p4[r] = __builtin_amdgcn_exp2f(tb);
        }
        rs[nj] += (p4[0] + p4[1]) + (p4[2] + p4[3]);
        pw[nj][mi * 2]     = pk2(p4[0], p4[1]);
        pw[nj][mi * 2 + 1] = pk2(p4[2], p4[3]);
      }
    bf16x8 pB[2];
#pragma unroll
    for (int nj = 0; nj < 2; ++nj) {
      union { unsigned u[4]; bf16x8 v; } pc;
      pc.u[0] = pw[nj][0]; pc.u[1] = pw[nj][1];
      pc.u[2] = pw[nj][2]; pc.u[3] = pw[nj][3];
      pB[nj] = pc.v;
    }

    // PV (phi cancels between pre-permuted V and lane-local P)
#pragma unroll
    for (int md = 0; md < 4; ++md)
#pragma unroll
      for (int nj = 0; nj < 2; ++nj)
        o[md][nj] = __builtin_amdgcn_mfma_f32_16x16x32_bf16(
            vA[md], pB[nj], o[md][nj], 0, 0, 0);

    __syncthreads();  // drains own DMA (tile+1) + protects parity flip
  }

  // merge the two K-halves (mgbuf aliases stage buffers, dead now)
  const int hs = wid & 1;
  if (kh == 1) {
#pragma unroll
    for (int md = 0; md < 4; ++md)
#pragma unroll
      for (int nj = 0; nj < 2; ++nj)
#pragma unroll
        for (int r = 0; r < 4; ++r)
          mgbuf[hs * 2176 + ((md * 2 + nj) * 4 + r) * 64 + lane] = o[md][nj][r];
    mgbuf[hs * 2176 + 32 * 64 + lane] = rs[0];
    mgbuf[hs * 2176 + 33 * 64 + lane] = rs[1];
  }
  __syncthreads();
  if (kh == 0) {
#pragma unroll
    for (int md = 0; md < 4; ++md)
#pragma unroll
      for (int nj = 0; nj < 2; ++nj)
#pragma unroll
        for (int r = 0; r < 4; ++r)
          o[md][nj][r] += mgbuf[hs * 2176 + ((md * 2 + nj) * 4 + r) * 64 + lane];
    rs[0] += mgbuf[hs * 2176 + 32 * 64 + lane];
    rs[1] += mgbuf[hs * 2176 + 33 * 64 + lane];
    float inv[2];
#pragma unroll
    for (int nj = 0; nj < 2; ++nj) {
      rs[nj] += __shfl_xor(rs[nj], 16);
      rs[nj] += __shfl_xor(rs[nj], 32);
      inv[nj] = __builtin_amdgcn_rcpf(rs[nj]);
    }
#pragma unroll
    for (int md = 0; md < 4; ++md)
#pragma unroll
      for (int nj = 0; nj < 2; ++nj) {
        int l = q0 + nj * 16 + lo;
        uint2 st = { pk2(o[md][nj][0] * inv[nj], o[md][nj][1] * inv[nj]),
                     pk2(o[md][nj][2] * inv[nj], o[md][nj][3] * inv[nj]) };
        *(uint2*)&ao[((size_t)b * LL + l) * DM + h * DH + md * 16 + quad * 4] = st;
      }
  }
}

// ---------------- K3: output projection, barrier-free K-loop (r10) ---------
__global__ __launch_bounds__(256) void oproj(
    const unsigned short* __restrict__ ao, const unsigned short* __restrict__ wob,
    float* __restrict__ out)
{
  const int m0 = blockIdx.y * 128;
  const int n0 = blockIdx.x * 64;
  __shared__ __align__(16) char arena[81920];
  const int tid = threadIdx.x;
  const int wid = tid >> 6;
  const int lane = tid & 63;
  const int lo = lane & 15;
  const int quad = lane >> 4;
  char* xpriv = arena + 65536 + wid * 4096;

  f32x4 acc[2][4];
#pragma unroll
  for (int mi = 0; mi < 2; ++mi)
#pragma unroll
    for (int ni = 0; ni < 4; ++ni) acc[mi][ni] = (f32x4)0.0f;

#pragma unroll
  for (int j = 0; j < 16; ++j) {
    int idx = j * 256 + tid, r = idx >> 6, c = idx & 63;
    async_copy16(arena + j * 4096 + wid * 1024,
                 wob + (size_t)(n0 + r) * DM + ((c ^ (r & 15)) * 8));
  }
#pragma unroll
  for (int j = 0; j < 2; ++j) {
    int idx = j * 64 + lane, r = idx >> 2, c = idx & 3;
    async_copy16(xpriv + j * 1024,
                 ao + (size_t)(m0 + wid * 32 + r) * DM + ((c ^ (r & 3)) * 8));
  }
  __syncthreads();  // the only barrier

  const unsigned short* Wb = (const unsigned short*)arena;
  for (int it = 0; it < 16; ++it) {
    const int p = it & 1;
    if (it < 15) {
      const int kk = (it + 1) * 32;
#pragma unroll
      for (int j = 0; j < 2; ++j) {
        int idx = j * 64 + lane, r = idx >> 2, c = idx & 3;
        async_copy16(xpriv + (1 - p) * 2048 + j * 1024,
                     ao + (size_t)(m0 + wid * 32 + r) * DM + kk +
                         ((c ^ (r & 3)) * 8));
      }
      asm volatile("" ::: "memory");
      asm volatile("s_waitcnt vmcnt(2)" ::: "memory");
    } else {
      asm volatile("s_waitcnt vmcnt(0)" ::: "memory");
    }
    const unsigned short* Ab = (const unsigned short*)(xpriv + p * 2048);
    bf16x8 a[2], bfr[4];
#pragma unroll
    for (int mi = 0; mi < 2; ++mi) {
      int R = mi * 16 + lo;
      a[mi] = *(const bf16x8*)&Ab[R * 32 + ((quad ^ (R & 3)) * 8)];
    }
#pragma unroll
    for (int ni = 0; ni < 4; ++ni) {
      int N = ni * 16 + lo;
      bfr[ni] = *(const bf16x8*)&Wb[N * 512 + (((it * 4 + quad) ^ (N & 15)) * 8)];
    }
#pragma unroll
    for (int mi = 0; mi < 2; ++mi)
#pragma unroll
      for (int ni = 0; ni < 4; ++ni)
        acc[mi][ni] = __builtin_amdgcn_mfma_f32_16x16x32_bf16(
            a[mi], bfr[ni], acc[mi][ni], 0, 0, 0);
  }

#pragma unroll
  for (int mi = 0; mi < 2; ++mi)
#pragma unroll
    for (int ni = 0; ni < 4; ++ni)
#pragma unroll
      for (int r = 0; r < 4; ++r)
        out[(size_t)(m0 + wid * 32 + mi * 16 + quad * 4 + r) * DM +
            n0 + ni * 16 + lo] = acc[mi][ni][r];
}

extern "C" void kernel_launch(void* const* d_in, const int* in_sizes, int n_in,
                              void* d_out, int out_size, void* d_ws, size_t ws_size,
                              hipStream_t stream) {
  const float* qin = (const float*)d_in[0];
  const float* kin = (const float*)d_in[1];
  const float* vin = (const float*)d_in[2];
  const int*   msk = (const int*)d_in[3];
  const float* adj = (const float*)d_in[4];
  const float* dis = (const float*)d_in[5];
  const float* wq  = (const float*)d_in[6];
  const float* wk  = (const float*)d_in[7];
  const float* wv  = (const float*)d_in[8];
  const float* wo  = (const float*)d_in[9];
  const float* la  = (const float*)d_in[10];
  const float* ld  = (const float*)d_in[11];
  float* out = (float*)d_out;

  const size_t tensb = (size_t)BB * HH * LL * DH;   // 4,194,304
  const size_t xsz   = (size_t)BB * LL * DIN;       // 2,097,152
  unsigned short* qb  = (unsigned short*)d_ws;
  unsigned short* kb  = qb + tensb;
  unsigned short* vt  = kb + tensb;
  unsigned short* ao  = vt + tensb;                 // (B,L,512) bf16
  unsigned short* xq  = ao;                         // alias (dead until attn)
  unsigned short* xk  = ao + xsz;
  unsigned short* xv  = ao + tensb;
  unsigned short* wqb = xv + xsz;
  unsigned short* wkb = wqb + (size_t)DM * DIN;
  unsigned short* wvb = wkb + (size_t)DM * DIN;
  unsigned short* wob = wvb + (size_t)DM * DIN;
  float*          mdd = (float*)(wob + (size_t)DM * DM);
  unsigned short* bpk = (unsigned short*)(mdd + (size_t)BB * LL);  // 16.8 MB

  prep<<<dim3(10888), 256, 0, stream>>>(qin, kin, vin, wq, wk, wv, wo, msk,
                                        adj, dis,
                                        xq, xk, xv, wqb, wkb, wvb, wob, mdd, bpk);
  qkv_proj<<<dim3(8, 64, 3), 256, 0, stream>>>(xq, xk, xv, wqb, wkb, wvb, qb, kb, vt);
  attn<<<dim3(1024), 256, 0, stream>>>(qb, kb, vt, mdd, bpk, la, ld, ao);
  oproj<<<dim3(8, 64), 256, 0, stream>>>(ao, wob, out);
}

// Round 13
// 226.295 us; speedup vs baseline: 1.0797x; 1.0196x over previous
//
#include <hip/hip_runtime.h>
#include <hip/hip_fp16.h>

#define BB 8
#define LL 1024
#define DIN 256
#define DM 512
#define HH 8
#define DH 64

typedef __attribute__((ext_vector_type(8))) short bf16x8;
typedef __attribute__((ext_vector_type(4))) float f32x4;

__device__ __forceinline__ unsigned short f2bf(float f) {
  union { float f; unsigned u; } c; c.f = f;
  unsigned u = c.u;
  return (unsigned short)((u + 0x7fffu + ((u >> 16) & 1u)) >> 16);
}

#if defined(__has_builtin)
#if __has_builtin(__builtin_amdgcn_cvt_pk_bf16_f32)
#define HAS_PK_BF16 1
#endif
#endif

#if defined(HAS_PK_BF16)
typedef __bf16 bf2 __attribute__((ext_vector_type(2)));
__device__ __forceinline__ unsigned pk2(float lo, float hi) {
  union { bf2 v; unsigned u; } c;
  c.v = __builtin_amdgcn_cvt_pk_bf16_f32(lo, hi);
  return c.u;
}
#else
__device__ __forceinline__ unsigned pk2(float lo, float hi) {
  return ((unsigned)f2bf(hi) << 16) | f2bf(lo);
}
#endif

// 16-bit bias pack: dis as f16 rounded to the 15-bit (even-LSB) grid,
// binary adj in the stolen LSB (validated r12: absmax unchanged).
__device__ __forceinline__ unsigned pk16(float a, float d) {
  unsigned v = (unsigned)__half_as_ushort(__float2half_rn(d));
  v = (v + 1u) & 0xFFFEu;           // round-to-nearest on 15-bit grid
  return v | (a > 0.5f ? 1u : 0u);
}
__device__ __forceinline__ unsigned pk16x2(float a0, float d0,
                                           float a1, float d1) {
  return pk16(a0, d0) | (pk16(a1, d1) << 16);
}

// async global -> LDS DMA, 16 B/lane; LDS dest = wave-uniform base + lane*16
__device__ __forceinline__ void async_copy16(void* lds, const void* g) {
  __builtin_amdgcn_global_load_lds(
      (const __attribute__((address_space(1))) unsigned*)g,
      (__attribute__((address_space(3))) unsigned*)lds, 16, 0, 0);
}

// ---------------- K0: merged precast (u16 bias pack) ----------------
__global__ __launch_bounds__(256) void prep(
    const float* __restrict__ qin, const float* __restrict__ kin,
    const float* __restrict__ vin,
    const float* __restrict__ wq, const float* __restrict__ wk,
    const float* __restrict__ wv, const float* __restrict__ wo,
    const int* __restrict__ msk,
    const float* __restrict__ adj, const float* __restrict__ dis,
    unsigned short* __restrict__ xq, unsigned short* __restrict__ xk,
    unsigned short* __restrict__ xv,
    unsigned short* __restrict__ wqb, unsigned short* __restrict__ wkb,
    unsigned short* __restrict__ wvb, unsigned short* __restrict__ wob,
    float* __restrict__ mad, unsigned short* __restrict__ bp)
{
  int t = blockIdx.x * 256 + threadIdx.x;
  const int XS = 524288, WS = 32768;
  if (t < 3 * XS) {
    int seg = t >> 19, off = t & (XS - 1);
    const float* s = (seg == 0) ? qin : (seg == 1) ? kin : vin;
    unsigned short* d = (seg == 0) ? xq : (seg == 1) ? xk : xv;
    float4 f = ((const float4*)s)[off];
    uint2 o = { pk2(f.x, f.y), pk2(f.z, f.w) };
    ((uint2*)d)[off] = o;
    return;
  }
  t -= 3 * XS;
  if (t < 3 * WS) {
    int seg = t >> 15, off = t & (WS - 1);
    const float* s = (seg == 0) ? wq : (seg == 1) ? wk : wv;
    unsigned short* d = (seg == 0) ? wqb : (seg == 1) ? wkb : wvb;
    float4 f = ((const float4*)s)[off];
    uint2 o = { pk2(f.x, f.y), pk2(f.z, f.w) };
    ((uint2*)d)[off] = o;
    return;
  }
  t -= 3 * WS;
  if (t < 65536) {
    float4 f = ((const float4*)wo)[t];
    uint2 o = { pk2(f.x, f.y), pk2(f.z, f.w) };
    ((uint2*)wob)[t] = o;
    return;
  }
  t -= 65536;
  if (t < 2048) {
    int4 m = ((const int4*)msk)[t];
    float4 f = { m.x ? 0.0f : -30000.0f, m.y ? 0.0f : -30000.0f,
                 m.z ? 0.0f : -30000.0f, m.w ? 0.0f : -30000.0f };
    ((float4*)mad)[t] = f;
    return;
  }
  t -= 2048;  // u16 bias pack: 1,048,576 threads x 8 elements
  if (t < 1048576) {
    float4 a0 = ((const float4*)adj)[t * 2];
    float4 a1 = ((const float4*)adj)[t * 2 + 1];
    float4 d0 = ((const float4*)dis)[t * 2];
    float4 d1 = ((const float4*)dis)[t * 2 + 1];
    uint4 o = { pk16x2(a0.x, d0.x, a0.y, d0.y),
                pk16x2(a0.z, d0.z, a0.w, d0.w),
                pk16x2(a1.x, d1.x, a1.y, d1.y),
                pk16x2(a1.z, d1.z, a1.w, d1.w) };
    ((uint4*)bp)[t] = o;
  }
}

// ---------------- K1: QKV projection, barrier-free K-loop (r10) ------------
__global__ __launch_bounds__(256) void qkv_proj(
    const unsigned short* __restrict__ xq, const unsigned short* __restrict__ xk,
    const unsigned short* __restrict__ xv,
    const unsigned short* __restrict__ wqb, const unsigned short* __restrict__ wkb,
    const unsigned short* __restrict__ wvb,
    unsigned short* __restrict__ qb, unsigned short* __restrict__ kb,
    unsigned short* __restrict__ vt)
{
  const int t = blockIdx.z;
  const unsigned short* __restrict__ X = (t == 0) ? xq : (t == 1) ? xk : xv;
  const unsigned short* __restrict__ W = (t == 0) ? wqb : (t == 1) ? wkb : wvb;
  const int m0 = blockIdx.y * 128;
  const int h  = blockIdx.x;
  // arena: W static 32768 | X 4 waves x (2 parity x 2048) = 49152 B
  __shared__ __align__(16) char arena[49152];
  const int tid = threadIdx.x;
  const int wid = tid >> 6;
  const int lane = tid & 63;
  const int lo = lane & 15;
  const int quad = lane >> 4;
  char* xpriv = arena + 32768 + wid * 4096;

  f32x4 acc[2][4];
#pragma unroll
  for (int mi = 0; mi < 2; ++mi)
#pragma unroll
    for (int ni = 0; ni < 4; ++ni) acc[mi][ni] = (f32x4)0.0f;

#pragma unroll
  for (int j = 0; j < 8; ++j) {
    int idx = j * 256 + tid, r = idx >> 5, c = idx & 31;
    async_copy16(arena + j * 4096 + wid * 1024,
                 W + (size_t)(h * 64 + r) * DIN + ((c ^ (r & 15)) * 8));
  }
#pragma unroll
  for (int j = 0; j < 2; ++j) {
    int idx = j * 64 + lane, r = idx >> 2, c = idx & 3;
    async_copy16(xpriv + j * 1024,
                 X + (size_t)(m0 + wid * 32 + r) * DIN + ((c ^ (r & 3)) * 8));
  }
  __syncthreads();  // drains W + X(0); the only barrier

  const unsigned short* Wb = (const unsigned short*)arena;
  for (int it = 0; it < 8; ++it) {
    const int p = it & 1;
    if (it < 7) {
      const int kk = (it + 1) * 32;
#pragma unroll
      for (int j = 0; j < 2; ++j) {
        int idx = j * 64 + lane, r = idx >> 2, c = idx & 3;
        async_copy16(xpriv + (1 - p) * 2048 + j * 1024,
                     X + (size_t)(m0 + wid * 32 + r) * DIN + kk +
                         ((c ^ (r & 3)) * 8));
      }
      asm volatile("" ::: "memory");
      asm volatile("s_waitcnt vmcnt(2)" ::: "memory");
    } else {
      asm volatile("s_waitcnt vmcnt(0)" ::: "memory");
    }
    const unsigned short* Ab = (const unsigned short*)(xpriv + p * 2048);
    bf16x8 a[2], bfr[4];
#pragma unroll
    for (int mi = 0; mi < 2; ++mi) {
      int R = mi * 16 + lo;
      a[mi] = *(const bf16x8*)&Ab[R * 32 + ((quad ^ (R & 3)) * 8)];
    }
#pragma unroll
    for (int ni = 0; ni < 4; ++ni) {
      int N = ni * 16 + lo;
      bfr[ni] = *(const bf16x8*)&Wb[N * 256 + (((it * 4 + quad) ^ (N & 15)) * 8)];
    }
#pragma unroll
    for (int mi = 0; mi < 2; ++mi)
#pragma unroll
      for (int ni = 0; ni < 4; ++ni)
        acc[mi][ni] = __builtin_amdgcn_mfma_f32_16x16x32_bf16(
            a[mi], bfr[ni], acc[mi][ni], 0, 0, 0);
  }

  const int b = m0 >> 10;
  const int lbase0 = (m0 & 1023) + wid * 32;
  if (t < 2) {
    unsigned short* dstp = (t == 0) ? qb : kb;
#pragma unroll
    for (int mi = 0; mi < 2; ++mi)
#pragma unroll
      for (int ni = 0; ni < 4; ++ni) {
        int d = ni * 16 + lo;
#pragma unroll
        for (int r = 0; r < 4; ++r) {
          int lb = lbase0 + mi * 16 + quad * 4 + r;
          dstp[((size_t)(b * HH + h) * LL + lb) * DH + d] = f2bf(acc[mi][ni][r]);
        }
      }
  } else {
#pragma unroll
    for (int mi = 0; mi < 2; ++mi)
#pragma unroll
      for (int ni = 0; ni < 4; ++ni) {
        int d = ni * 16 + lo;
        int lb = lbase0 + quad * 8 + mi * 4;  // phi-permuted within 32-block
        uint2 o = { pk2(acc[mi][ni][0], acc[mi][ni][1]),
                    pk2(acc[mi][ni][2], acc[mi][ni][3]) };
        *(uint2*)&vt[((size_t)(b * HH + h) * DH + d) * LL + lb] = o;
      }
  }
}

// ---------------- K2: attn, minimum-LDS wave-private pipeline --------------
// All staging wave-private, NO main-loop barrier. K SINGLE-buffered (4KB):
// K-DMA(t+1) issues only after lgkmcnt(0) drains tile-t ds_reads -> safe
// overwrite; its latency hides under softmax+PV. Bias (HBM) keeps a 2x2KB
// u16 double-buffer staged one tile ahead. LDS/wave = 8KB -> 32768/block
// = 5 blocks/CU (20 waves/CU, ~2x every prior working variant) — decisive
// test of the TLP-starvation theory (r12 refuted bytes; r8 refuted barrier).
// vmcnt FIFO audit (issue order/tile: biasDMA(t+1) 2 | V+mask 5 | [ds] |
// lgkm0; K-DMA(t+1) 4): tile-top wait vmcnt(7) retires K(t) (and bias(t),
// issued earlier); t=15: vmcnt(5). Prologue [bias0 2 | K0 4] satisfies the
// same count at t=0.
// grid 1024: idx = qt*32 + hg*8 + b. 4 waves: (h = hg*2 + wid&1, kh = wid>>1).
__global__ __launch_bounds__(256) void attn(
    const unsigned short* __restrict__ qb, const unsigned short* __restrict__ kb,
    const unsigned short* __restrict__ vt,
    const float* __restrict__ mad, const unsigned short* __restrict__ bp,
    const float* __restrict__ la_, const float* __restrict__ ld_,
    unsigned short* __restrict__ ao)
{
  const int bi = blockIdx.x;
  const int b  = bi & 7;
  const int hg = (bi >> 3) & 3;
  const int q0 = (bi >> 5) * 32;
  const int tid = threadIdx.x;
  const int wid = tid >> 6;
  const int lane = tid & 63;
  const int lo = lane & 15;
  const int quad = lane >> 4;
  const int h  = hg * 2 + (wid & 1);
  const int kh = wid >> 1;
  const int bh = b * HH + h;

  // arena: K single 4x4096 | bias dbuf 4x(2x2048) = 32768 B; merge alias after
  __shared__ __align__(16) char arena[32768];
  char* kpriv = arena + wid * 4096;            // wave-private single K buf
  char* bpriv = arena + 16384 + wid * 4096;    // wave-private bias, 2 parities
  float* mgbuf = (float*)arena;  // merge alias (post-loop, staging dead)

  const float LOG2E = 1.44269504f;
  const float la2 = la_[h] * LOG2E, ld2 = ld_[h] * LOG2E;
  const float sc2 = 0.125f * LOG2E;

  const unsigned short* qp = qb + ((size_t)bh * LL + q0) * DH;
  bf16x8 qB[2][2];
#pragma unroll
  for (int nj = 0; nj < 2; ++nj)
#pragma unroll
    for (int ki = 0; ki < 2; ++ki)
      qB[nj][ki] = *(const bf16x8*)&qp[(nj * 16 + lo) * DH + ki * 32 + quad * 8];

  const unsigned short* kp = kb + (size_t)bh * LL * DH;
  const unsigned short* vp = vt + (size_t)bh * DH * LL;
  const unsigned short* bpp = bp + ((size_t)b * LL + q0) * LL;
  const float* mp = mad + b * LL;

  f32x4 o[4][2];
  float rs[2] = {0.0f, 0.0f};
#pragma unroll
  for (int md = 0; md < 4; ++md)
#pragma unroll
    for (int nj = 0; nj < 2; ++nj) o[md][nj] = (f32x4)0.0f;

  const int kbeg = kh * (LL / 2);
  const int r8 = lane >> 3, p8 = lane & 7;
  const int br = lane >> 2;            // bias row within 16-row group
  const int bsw = ((((lane & 3) << 1) ^ (br & 6)) << 2);  // u16 col, swizzled

  // prologue: bias(0) -> parity 0 (2 ops), K(0) -> single buf (4 ops)
  {
    const unsigned short* bg = bpp + kh * (LL / 2);
#pragma unroll
    for (int j = 0; j < 2; ++j)
      async_copy16(bpriv + j * 1024, bg + (size_t)(j * 16 + br) * LL + bsw);
    const unsigned short* kg = kp + (size_t)kbeg * DH;
#pragma unroll
    for (int j = 0; j < 4; ++j)
      async_copy16(kpriv + j * 1024, kg + (j * 8 + r8) * 64 + ((p8 ^ r8) * 8));
  }
  // no barrier: wave-private staging, readiness via counted vmcnt

  for (int jt = 0; jt < 16; ++jt) {
    const int p = jt & 1;
    const int k0 = kbeg + jt * 32;

    // A: bias(t+1) DMA into alt parity (full-tile latency cover for HBM)
    if (jt < 15) {
      const unsigned short* bg = bpp + kh * (LL / 2) + (jt + 1) * 32;
#pragma unroll
      for (int j = 0; j < 2; ++j)
        async_copy16(bpriv + (1 - p) * 2048 + j * 1024,
                     bg + (size_t)(j * 16 + br) * LL + bsw);
    }

    // B: V (phi-ordered, 16B) + mask for THIS tile
    bf16x8 vA[4];
#pragma unroll
    for (int md = 0; md < 4; ++md)
      vA[md] = *(const bf16x8*)&vp[(md * 16 + lo) * LL + k0 + quad * 8];
    f32x4 msv[2];
#pragma unroll
    for (int mi = 0; mi < 2; ++mi)
      msv[mi] = *(const f32x4*)&mp[k0 + mi * 16 + quad * 4];
    asm volatile("" ::: "memory");

    // C: retire K(t) (+ bias(t), issued earlier in FIFO)
    if (jt < 15) {
      asm volatile("s_waitcnt vmcnt(7)" ::: "memory");
    } else {
      asm volatile("s_waitcnt vmcnt(5)" ::: "memory");
    }

    // D: all LDS reads for this tile -> regs
    bf16x8 kA[2][2];
#pragma unroll
    for (int mi = 0; mi < 2; ++mi)
#pragma unroll
      for (int ki = 0; ki < 2; ++ki)
        kA[mi][ki] = *(const bf16x8*)&((const unsigned short*)kpriv)
            [(mi * 16 + lo) * 64 + (((ki * 4 + quad) ^ (lo & 7)) * 8)];
    const unsigned short* bbf = (const unsigned short*)(bpriv + p * 2048);
    uint2 w[2][2];
#pragma unroll
    for (int mi = 0; mi < 2; ++mi)
#pragma unroll
      for (int nj = 0; nj < 2; ++nj)
        w[mi][nj] = *(const uint2*)&bbf[(nj * 16 + lo) * 32 +
                                        (((mi * 4 + quad) ^ (lo & 6)) << 2)];

    // E: LDS reads drained -> safe to overwrite single K buf with K(t+1)
    asm volatile("s_waitcnt lgkmcnt(0)" ::: "memory");
    if (jt < 15) {
      const unsigned short* kg = kp + (size_t)(k0 + 32) * DH;
#pragma unroll
      for (int j = 0; j < 4; ++j)
        async_copy16(kpriv + j * 1024,
                     kg + (j * 8 + r8) * 64 + ((p8 ^ r8) * 8));
    }
    asm volatile("" ::: "memory");

    // QK^T (register operands only)
    f32x4 s[2][2];
#pragma unroll
    for (int mi = 0; mi < 2; ++mi)
#pragma unroll
      for (int nj = 0; nj < 2; ++nj) s[mi][nj] = (f32x4)0.0f;
#pragma unroll
    for (int ki = 0; ki < 2; ++ki)
#pragma unroll
      for (int mi = 0; mi < 2; ++mi)
#pragma unroll
        for (int nj = 0; nj < 2; ++nj)
          s[mi][nj] = __builtin_amdgcn_mfma_f32_16x16x32_bf16(
              kA[mi][ki], qB[nj][ki], s[mi][nj], 0, 0, 0);

    // softmax numerator from u16 bias regs + lane-local pack to B-frag
    unsigned pw[2][4];
#pragma unroll
    for (int mi = 0; mi < 2; ++mi)
#pragma unroll
      for (int nj = 0; nj < 2; ++nj) {
        float p4[4];
#pragma unroll
        for (int r = 0; r < 4; ++r) {
          unsigned xr = (((r & 2) ? w[mi][nj].y : w[mi][nj].x) >>
                         ((r & 1) * 16)) & 0xFFFFu;
          float dv = __half2float(__ushort_as_half(
              (unsigned short)(xr & 0xFFFEu)));
          float tb = fmaf(s[mi][nj][r], sc2, msv[mi][r]);
          tb = fmaf(dv, ld2, tb);
          tb += (xr & 1u) ? la2 : 0.0f;
          p4[r] = __builtin_amdgcn_exp2f(tb);
        }
        rs[nj] += (p4[0] + p4[1]) + (p4[2] + p4[3]);
        pw[nj][mi * 2]     = pk2(p4[0], p4[1]);
        pw[nj][mi * 2 + 1] = pk2(p4[2], p4[3]);
      }
    bf16x8 pB[2];
#pragma unroll
    for (int nj = 0; nj < 2; ++nj) {
      union { unsigned u[4]; bf16x8 v; } pc;
      pc.u[0] = pw[nj][0]; pc.u[1] = pw[nj][1];
      pc.u[2] = pw[nj][2]; pc.u[3] = pw[nj][3];
      pB[nj] = pc.v;
    }

    // PV (phi cancels between pre-permuted V and lane-local P)
#pragma unroll
    for (int md = 0; md < 4; ++md)
#pragma unroll
      for (int nj = 0; nj < 2; ++nj)
        o[md][nj] = __builtin_amdgcn_mfma_f32_16x16x32_bf16(
            vA[md], pB[nj], o[md][nj], 0, 0, 0);
    // no barrier — waves fully independent until the merge
  }

  __syncthreads();  // all waves done with private staging before mgbuf alias
  const int hs = wid & 1;
  if (kh == 1) {
#pragma unroll
    for (int md = 0; md < 4; ++md)
#pragma unroll
      for (int nj = 0; nj < 2; ++nj)
#pragma unroll
        for (int r = 0; r < 4; ++r)
          mgbuf[hs * 2176 + ((md * 2 + nj) * 4 + r) * 64 + lane] = o[md][nj][r];
    mgbuf[hs * 2176 + 32 * 64 + lane] = rs[0];
    mgbuf[hs * 2176 + 33 * 64 + lane] = rs[1];
  }
  __syncthreads();
  if (kh == 0) {
#pragma unroll
    for (int md = 0; md < 4; ++md)
#pragma unroll
      for (int nj = 0; nj < 2; ++nj)
#pragma unroll
        for (int r = 0; r < 4; ++r)
          o[md][nj][r] += mgbuf[hs * 2176 + ((md * 2 + nj) * 4 + r) * 64 + lane];
    rs[0] += mgbuf[hs * 2176 + 32 * 64 + lane];
    rs[1] += mgbuf[hs * 2176 + 33 * 64 + lane];
    float inv[2];
#pragma unroll
    for (int nj = 0; nj < 2; ++nj) {
      rs[nj] += __shfl_xor(rs[nj], 16);
      rs[nj] += __shfl_xor(rs[nj], 32);
      inv[nj] = __builtin_amdgcn_rcpf(rs[nj]);
    }
#pragma unroll
    for (int md = 0; md < 4; ++md)
#pragma unroll
      for (int nj = 0; nj < 2; ++nj) {
        int l = q0 + nj * 16 + lo;
        uint2 st = { pk2(o[md][nj][0] * inv[nj], o[md][nj][1] * inv[nj]),
                     pk2(o[md][nj][2] * inv[nj], o[md][nj][3] * inv[nj]) };
        *(uint2*)&ao[((size_t)b * LL + l) * DM + h * DH + md * 16 + quad * 4] = st;
      }
  }
}

// ---------------- K3: output projection, barrier-free K-loop (r10) ---------
__global__ __launch_bounds__(256) void oproj(
    const unsigned short* __restrict__ ao, const unsigned short* __restrict__ wob,
    float* __restrict__ out)
{
  const int m0 = blockIdx.y * 128;
  const int n0 = blockIdx.x * 64;
  __shared__ __align__(16) char arena[81920];
  const int tid = threadIdx.x;
  const int wid = tid >> 6;
  const int lane = tid & 63;
  const int lo = lane & 15;
  const int quad = lane >> 4;
  char* xpriv = arena + 65536 + wid * 4096;

  f32x4 acc[2][4];
#pragma unroll
  for (int mi = 0; mi < 2; ++mi)
#pragma unroll
    for (int ni = 0; ni < 4; ++ni) acc[mi][ni] = (f32x4)0.0f;

#pragma unroll
  for (int j = 0; j < 16; ++j) {
    int idx = j * 256 + tid, r = idx >> 6, c = idx & 63;
    async_copy16(arena + j * 4096 + wid * 1024,
                 wob + (size_t)(n0 + r) * DM + ((c ^ (r & 15)) * 8));
  }
#pragma unroll
  for (int j = 0; j < 2; ++j) {
    int idx = j * 64 + lane, r = idx >> 2, c = idx & 3;
    async_copy16(xpriv + j * 1024,
                 ao + (size_t)(m0 + wid * 32 + r) * DM + ((c ^ (r & 3)) * 8));
  }
  __syncthreads();  // the only barrier

  const unsigned short* Wb = (const unsigned short*)arena;
  for (int it = 0; it < 16; ++it) {
    const int p = it & 1;
    if (it < 15) {
      const int kk = (it + 1) * 32;
#pragma unroll
      for (int j = 0; j < 2; ++j) {
        int idx = j * 64 + lane, r = idx >> 2, c = idx & 3;
        async_copy16(xpriv + (1 - p) * 2048 + j * 1024,
                     ao + (size_t)(m0 + wid * 32 + r) * DM + kk +
                         ((c ^ (r & 3)) * 8));
      }
      asm volatile("" ::: "memory");
      asm volatile("s_waitcnt vmcnt(2)" ::: "memory");
    } else {
      asm volatile("s_waitcnt vmcnt(0)" ::: "memory");
    }
    const unsigned short* Ab = (const unsigned short*)(xpriv + p * 2048);
    bf16x8 a[2], bfr[4];
#pragma unroll
    for (int mi = 0; mi < 2; ++mi) {
      int R = mi * 16 + lo;
      a[mi] = *(const bf16x8*)&Ab[R * 32 + ((quad ^ (R & 3)) * 8)];
    }
#pragma unroll
    for (int ni = 0; ni < 4; ++ni) {
      int N = ni * 16 + lo;
      bfr[ni] = *(const bf16x8*)&Wb[N * 512 + (((it * 4 + quad) ^ (N & 15)) * 8)];
    }
#pragma unroll
    for (int mi = 0; mi < 2; ++mi)
#pragma unroll
      for (int ni = 0; ni < 4; ++ni)
        acc[mi][ni] = __builtin_amdgcn_mfma_f32_16x16x32_bf16(
            a[mi], bfr[ni], acc[mi][ni], 0, 0, 0);
  }

#pragma unroll
  for (int mi = 0; mi < 2; ++mi)
#pragma unroll
    for (int ni = 0; ni < 4; ++ni)
#pragma unroll
      for (int r = 0; r < 4; ++r)
        out[(size_t)(m0 + wid * 32 + mi * 16 + quad * 4 + r) * DM +
            n0 + ni * 16 + lo] = acc[mi][ni][r];
}

extern "C" void kernel_launch(void* const* d_in, const int* in_sizes, int n_in,
                              void* d_out, int out_size, void* d_ws, size_t ws_size,
                              hipStream_t stream) {
  const float* qin = (const float*)d_in[0];
  const float* kin = (const float*)d_in[1];
  const float* vin = (const float*)d_in[2];
  const int*   msk = (const int*)d_in[3];
  const float* adj = (const float*)d_in[4];
  const float* dis = (const float*)d_in[5];
  const float* wq  = (const float*)d_in[6];
  const float* wk  = (const float*)d_in[7];
  const float* wv  = (const float*)d_in[8];
  const float* wo  = (const float*)d_in[9];
  const float* la  = (const float*)d_in[10];
  const float* ld  = (const float*)d_in[11];
  float* out = (float*)d_out;

  const size_t tensb = (size_t)BB * HH * LL * DH;   // 4,194,304
  const size_t xsz   = (size_t)BB * LL * DIN;       // 2,097,152
  unsigned short* qb  = (unsigned short*)d_ws;
  unsigned short* kb  = qb + tensb;
  unsigned short* vt  = kb + tensb;
  unsigned short* ao  = vt + tensb;                 // (B,L,512) bf16
  unsigned short* xq  = ao;                         // alias (dead until attn)
  unsigned short* xk  = ao + xsz;
  unsigned short* xv  = ao + tensb;
  unsigned short* wqb = xv + xsz;
  unsigned short* wkb = wqb + (size_t)DM * DIN;
  unsigned short* wvb = wkb + (size_t)DM * DIN;
  unsigned short* wob = wvb + (size_t)DM * DIN;
  float*          mdd = (float*)(wob + (size_t)DM * DM);
  unsigned short* bpk = (unsigned short*)(mdd + (size_t)BB * LL);  // 16.8 MB

  prep<<<dim3(10888), 256, 0, stream>>>(qin, kin, vin, wq, wk, wv, wo, msk,
                                        adj, dis,
                                        xq, xk, xv, wqb, wkb, wvb, wob, mdd, bpk);
  qkv_proj<<<dim3(8, 64, 3), 256, 0, stream>>>(xq, xk, xv, wqb, wkb, wvb, qb, kb, vt);
  attn<<<dim3(1024), 256, 0, stream>>>(qb, kb, vt, mdd, bpk, la, ld, ao);
  oproj<<<dim3(8, 64), 256, 0, stream>>>(ao, wob, out);
}